// Round 12
// baseline (498.218 us; speedup 1.0000x reference)
//
#include <hip/hip_runtime.h>
#include <hip/hip_bf16.h>

#define THREADS 256
#define WPB 8
#define NWIN 16384
#define NBLK (NWIN / WPB)

typedef short bf16x8 __attribute__((ext_vector_type(8)));
typedef float f32x4 __attribute__((ext_vector_type(4)));

// ---- LDS pool (ushort units), per 256-thread block (4 blocks/CU).
// x:  [49][136] bf16 (input staging)
// kO: [49][136] bf16 (k during QKV/attn -> overlaid by attn-out for proj)
// vt: [128][52] bf16 (v transposed: rows=dims, cols=tokens 0..48 + pad)
// Whole k/vt region zeroed at prologue; all deliberate over-reads land on
// finite bf16 (pads, neighbor regions, zero guard).
#define XP 136
#define KP 136
#define VTP 52
#define X_OFF 0
#define K_OFF 6664
#define VT_OFF 13328
#define POOL_USHORTS 20016      // 40,032 B -> 4 blocks/CU

#define LOG2E 1.4426950408889634f
#define SCALE_Q 0.17677669529663689f   // 32^-0.5

// ws layout: comb[1024][4][49][52] f32, then wq (24 ch-tiles x 4 ks), then wp
#define COMB_FLOATS (1024 * 4 * 49 * 52)
#define COMB_BYTES  ((size_t)COMB_FLOATS * 4)
#define WQ_USHORTS (96 * 64 * 8)
#define WP_USHORTS (32 * 64 * 8)

static __device__ __forceinline__ unsigned short f2bf(float x) {
    union { __hip_bfloat16 b; unsigned short u; } c;
    c.b = __float2bfloat16(x);
    return c.u;
}
static __device__ __forceinline__ unsigned pack2bf(float lo, float hi) {
    return (unsigned)f2bf(lo) | ((unsigned)f2bf(hi) << 16);
}
static __device__ __forceinline__ ushort4 cvt4(float4 v) {
    ushort4 u; u.x = f2bf(v.x); u.y = f2bf(v.y); u.z = f2bf(v.z); u.w = f2bf(v.w);
    return u;
}

// ---------------- prep: fp32 weights -> pre-swizzled bf16 fragments ----------------
// wq group g = out-channel/16 (0..23), lane l16 = channel-in-tile, dims ks*32+lg*8.
__global__ __launch_bounds__(512)
void prep_weights(const float* __restrict__ qkv_w, const float* __restrict__ proj_w,
                  unsigned short* __restrict__ wq, unsigned short* __restrict__ wp)
{
    const int t = blockIdx.x * 512 + threadIdx.x;
    if (t < 96 * 64) {
        const int lane = t & 63, g = t >> 6;
        const int l16 = lane & 15, lg = lane >> 4;
        const int ks = g & 3, wn = g >> 2;                 // wn = channel-tile 0..23
        const int ch = wn * 16 + l16;
        const float s = (ch < 128) ? (SCALE_Q * LOG2E) : 1.0f;
        const float* p = qkv_w + (size_t)ch * 128 + ks * 32 + lg * 8;
        bf16x8 f;
#pragma unroll
        for (int j = 0; j < 8; ++j) f[j] = (short)f2bf(p[j] * s);
        *(bf16x8*)&wq[(size_t)t * 8] = f;
    } else if (t < 96 * 64 + 32 * 64) {
        const int t2 = t - 96 * 64;
        const int lane = t2 & 63, g = t2 >> 6;             // g = wv*4+ks, wv 0..7
        const int l16 = lane & 15, lg = lane >> 4;
        const int ks = g & 3, wv = g >> 2;
        const float* p = proj_w + (size_t)(wv * 16 + l16) * 128 + ks * 32 + lg * 8;
        bf16x8 f;
#pragma unroll
        for (int j = 0; j < 8; ++j) f[j] = (short)f2bf(p[j]);
        *(bf16x8*)&wp[(size_t)t2 * 8] = f;
    }
}

// ---------------- prep: comb[wi][h][qt][52] = (mask + rel_bias) * log2e ----------------
__global__ __launch_bounds__(512)
void prep_comb(const float* __restrict__ mask, const float* __restrict__ bias_table,
               const int* __restrict__ rel_index, float* __restrict__ comb)
{
    const unsigned t = blockIdx.x * 512 + threadIdx.x;
    if (t >= 1024u * 4u * 49u * 49u) return;
    const unsigned wi = t / 9604u;            // 4*49*49
    const unsigned r1 = t - wi * 9604u;
    const unsigned h  = r1 / 2401u;
    const unsigned r2 = r1 - h * 2401u;       // qt*49 + kt
    const unsigned qt = r2 / 49u;
    const unsigned kt = r2 - qt * 49u;
    const float m = mask[wi * 2401u + r2];
    const float b = bias_table[rel_index[r2] * 4 + h];
    comb[(((size_t)wi * 4u + h) * 49u + qt) * 52u + kt] = (m + b) * LOG2E;
}

__global__ __launch_bounds__(THREADS, 4)
void winattn_kernel(const float* __restrict__ x, const float* __restrict__ comb,
                    const unsigned short* __restrict__ wq, const unsigned short* __restrict__ wpr,
                    const float* __restrict__ qkv_b, const float* __restrict__ proj_b,
                    float* __restrict__ out)
{
    __shared__ __align__(16) unsigned short pool[POOL_USHORTS];

    const int tid  = threadIdx.x;
    const int h    = tid >> 6;       // wave = head
    const int lane = tid & 63;
    const int lg   = lane >> 4;
    const int l16  = lane & 15;

    // C-layout -> A/B-fragment cross-lane permutation (verified template)
    const int idxA = l16 + 2 * (lane & 16);    // l16 + 32*(lg&1)
    const int idxB = idxA + 16;
    const bool hiSel = (lane & 32) != 0;       // lg>>1

    const int win0 = blockIdx.x * WPB;

    // ---------------- prologue: zero k+vt+guard, stage window 0 ----------------
    {
        unsigned* p32 = (unsigned*)pool;
        for (int i = K_OFF / 2 + tid; i < POOL_USHORTS / 2; i += THREADS) p32[i] = 0;
    }
#pragma unroll
    for (int it = 0; it < 7; ++it) {
        const int e = it * 1024 + tid * 4;
        if (e < 6272) {
            float4 v = *(const float4*)(x + (size_t)win0 * 6272 + e);
            *(ushort4*)&pool[X_OFF + (e >> 7) * XP + (e & 127)] = cvt4(v);
        }
    }
    __syncthreads();

    for (int w = 0; w < WPB; ++w) {
        const int win = win0 + w;
        const bool pf = (w + 1 < WPB);

        uintptr_t wqu = (uintptr_t)wq;
        asm volatile("" : "+s"(wqu));
        const unsigned short* wqx = (const unsigned short*)wqu;

        // -------- QKV (all wave-private: head h's 32 dims of q,k,v) --------
        // k: channels 128 + h*32 + nt*16; C col=token -> row write into kO
#pragma unroll
        for (int nt = 0; nt < 2; ++nt) {
            bf16x8 wB[4];
#pragma unroll
            for (int ks = 0; ks < 4; ++ks)
                wB[ks] = *(const bf16x8*)&wqx[(size_t)(((8 + 2 * h + nt) * 4 + ks) * 64 + lane) * 8];
            const float4 kb = *(const float4*)(qkv_b + 128 + h * 32 + nt * 16 + lg * 4);
#pragma unroll
            for (int mt = 0; mt < 4; ++mt) {
                bf16x8 xf[4];
#pragma unroll
                for (int ks = 0; ks < 4; ++ks)
                    xf[ks] = *(const bf16x8*)&pool[X_OFF + (mt * 16 + l16) * XP + ks * 32 + lg * 8];
                f32x4 acc = (f32x4){0.f, 0.f, 0.f, 0.f};
#pragma unroll
                for (int ks = 0; ks < 4; ++ks)
                    acc = __builtin_amdgcn_mfma_f32_16x16x32_bf16(wB[ks], xf[ks], acc, 0, 0, 0);
                const int tok = mt * 16 + l16;
                if (tok < 49) {
                    float4 v; v.x = acc[0] + kb.x; v.y = acc[1] + kb.y;
                    v.z = acc[2] + kb.z; v.w = acc[3] + kb.w;
                    *(ushort4*)&pool[K_OFF + tok * KP + h * 32 + nt * 16 + lg * 4] = cvt4(v);
                }
            }
        }
        // v: channels 256 + h*32 + nt*16; C col=channel -> transposed write into vt
#pragma unroll
        for (int nt = 0; nt < 2; ++nt) {
            bf16x8 wB[4];
#pragma unroll
            for (int ks = 0; ks < 4; ++ks)
                wB[ks] = *(const bf16x8*)&wqx[(size_t)(((16 + 2 * h + nt) * 4 + ks) * 64 + lane) * 8];
            const float vb = qkv_b[256 + h * 32 + nt * 16 + l16];
#pragma unroll
            for (int mt = 0; mt < 4; ++mt) {
                bf16x8 xf[4];
#pragma unroll
                for (int ks = 0; ks < 4; ++ks)
                    xf[ks] = *(const bf16x8*)&pool[X_OFF + (mt * 16 + l16) * XP + ks * 32 + lg * 8];
                f32x4 acc = (f32x4){0.f, 0.f, 0.f, 0.f};
#pragma unroll
                for (int ks = 0; ks < 4; ++ks)
                    acc = __builtin_amdgcn_mfma_f32_16x16x32_bf16(xf[ks], wB[ks], acc, 0, 0, 0);
                const int vcol = mt * 16 + lg * 4;
                if (vcol <= 48) {   // tokens 49-51 land in pad cols; >=52 skipped
                    float4 v; v.x = acc[0] + vb; v.y = acc[1] + vb;
                    v.z = acc[2] + vb; v.w = acc[3] + vb;
                    *(ushort4*)&pool[VT_OFF + (h * 32 + nt * 16 + l16) * VTP + vcol] = cvt4(v);
                }
            }
        }
        // q: channels h*32 + nt*16 (pre-scaled) -> packed bf16 in registers
        unsigned qP[4][2][2];
#pragma unroll
        for (int nt = 0; nt < 2; ++nt) {
            bf16x8 wB[4];
#pragma unroll
            for (int ks = 0; ks < 4; ++ks)
                wB[ks] = *(const bf16x8*)&wqx[(size_t)(((2 * h + nt) * 4 + ks) * 64 + lane) * 8];
            float4 qb = *(const float4*)(qkv_b + h * 32 + nt * 16 + lg * 4);
            qb.x *= SCALE_Q * LOG2E; qb.y *= SCALE_Q * LOG2E;
            qb.z *= SCALE_Q * LOG2E; qb.w *= SCALE_Q * LOG2E;
#pragma unroll
            for (int tq = 0; tq < 4; ++tq) {
                bf16x8 xf[4];
#pragma unroll
                for (int ks = 0; ks < 4; ++ks)
                    xf[ks] = *(const bf16x8*)&pool[X_OFF + (tq * 16 + l16) * XP + ks * 32 + lg * 8];
                f32x4 acc = (f32x4){0.f, 0.f, 0.f, 0.f};
#pragma unroll
                for (int ks = 0; ks < 4; ++ks)
                    acc = __builtin_amdgcn_mfma_f32_16x16x32_bf16(wB[ks], xf[ks], acc, 0, 0, 0);
                qP[tq][nt][0] = pack2bf(acc[0] + qb.x, acc[1] + qb.y);
                qP[tq][nt][1] = pack2bf(acc[2] + qb.z, acc[3] + qb.w);
            }
        }

        // hoist ak: read ALL k fragments before O overlays the k region (in-wave RAW)
        bf16x8 ak[4];
#pragma unroll
        for (int mt = 0; mt < 4; ++mt)
            ak[mt] = *(const bf16x8*)&pool[K_OFF + (mt * 16 + l16) * KP + h * 32 + lg * 8];

        const float* combW = comb + ((size_t)((win & 1023) * 4 + h)) * (49 * 52);

        // -------- attention + PV per q-tile (no cross-wave sync) --------
#pragma unroll
        for (int tq = 0; tq < 4; ++tq) {
            // bq B-fragment from qP via verified shfl permutation
            unsigned bqw[4];
            {
                const unsigned a0 = (unsigned)__shfl((int)qP[tq][0][0], idxA, 64);
                const unsigned a1 = (unsigned)__shfl((int)qP[tq][0][1], idxA, 64);
                const unsigned a2 = (unsigned)__shfl((int)qP[tq][0][0], idxB, 64);
                const unsigned a3 = (unsigned)__shfl((int)qP[tq][0][1], idxB, 64);
                const unsigned b0 = (unsigned)__shfl((int)qP[tq][1][0], idxA, 64);
                const unsigned b1 = (unsigned)__shfl((int)qP[tq][1][1], idxA, 64);
                const unsigned b2 = (unsigned)__shfl((int)qP[tq][1][0], idxB, 64);
                const unsigned b3 = (unsigned)__shfl((int)qP[tq][1][1], idxB, 64);
                bqw[0] = hiSel ? b0 : a0;
                bqw[1] = hiSel ? b1 : a1;
                bqw[2] = hiSel ? b2 : a2;
                bqw[3] = hiSel ? b3 : a3;
            }
            const bf16x8 bq = *(const bf16x8*)bqw;
            const int qt = tq * 16 + l16;
            const float* crow = combW + ((qt > 48) ? 48 : qt) * 52;

            f32x4 S[4];
            __builtin_amdgcn_s_setprio(1);
#pragma unroll
            for (int mt = 0; mt < 4; ++mt)
                S[mt] = __builtin_amdgcn_mfma_f32_16x16x32_bf16(ak[mt], bq, (f32x4){0.f,0.f,0.f,0.f}, 0, 0, 0);
            __builtin_amdgcn_s_setprio(0);

            float sum = 0.f;
            unsigned pk[4][2];
#pragma unroll
            for (int mt = 0; mt < 3; ++mt) {
                const float4 c = *(const float4*)(crow + mt * 16 + lg * 4);
                const float e0 = exp2f(S[mt][0] + c.x);
                const float e1 = exp2f(S[mt][1] + c.y);
                const float e2 = exp2f(S[mt][2] + c.z);
                const float e3 = exp2f(S[mt][3] + c.w);
                sum += (e0 + e1) + (e2 + e3);
                pk[mt][0] = pack2bf(e0, e1);
                pk[mt][1] = pack2bf(e2, e3);
            }
            const float e48 = (lg == 0) ? exp2f(S[3][0] + crow[48]) : 0.f;   // kt=48; kt>48 masked
            sum += e48;
            pk[3][0] = pack2bf(e48, 0.f);
            pk[3][1] = 0u;

            sum += __shfl_xor(sum, 16);
            sum += __shfl_xor(sum, 32);
            const float inv = 1.0f / sum;

            f32x4 O0 = (f32x4){0.f,0.f,0.f,0.f}, O1 = (f32x4){0.f,0.f,0.f,0.f};
#pragma unroll
            for (int kh = 0; kh < 2; ++kh) {
                const bf16x8 bv0 = *(const bf16x8*)&pool[VT_OFF + (h * 32 + l16) * VTP + kh * 32 + lg * 8];
                const bf16x8 bv1 = *(const bf16x8*)&pool[VT_OFF + (h * 32 + 16 + l16) * VTP + kh * 32 + lg * 8];
                unsigned pau[4];
                {
                    const unsigned pa0 = (unsigned)__shfl((int)pk[2 * kh + 0][0], idxA, 64);
                    const unsigned pa1 = (unsigned)__shfl((int)pk[2 * kh + 0][1], idxA, 64);
                    const unsigned pa2 = (unsigned)__shfl((int)pk[2 * kh + 0][0], idxB, 64);
                    const unsigned pa3 = (unsigned)__shfl((int)pk[2 * kh + 0][1], idxB, 64);
                    const unsigned pb0 = (unsigned)__shfl((int)pk[2 * kh + 1][0], idxA, 64);
                    const unsigned pb1 = (unsigned)__shfl((int)pk[2 * kh + 1][1], idxA, 64);
                    const unsigned pb2 = (unsigned)__shfl((int)pk[2 * kh + 1][0], idxB, 64);
                    const unsigned pb3 = (unsigned)__shfl((int)pk[2 * kh + 1][1], idxB, 64);
                    pau[0] = hiSel ? pb0 : pa0;
                    pau[1] = hiSel ? pb1 : pa1;
                    pau[2] = hiSel ? pb2 : pa2;
                    pau[3] = hiSel ? pb3 : pa3;
                }
                const bf16x8 pa = *(const bf16x8*)pau;
                __builtin_amdgcn_s_setprio(1);
                O0 = __builtin_amdgcn_mfma_f32_16x16x32_bf16(bv0, pa, O0, 0, 0, 0);
                O1 = __builtin_amdgcn_mfma_f32_16x16x32_bf16(bv1, pa, O1, 0, 0, 0);
                __builtin_amdgcn_s_setprio(0);
            }
            // attn-out overlays k region (head-private columns; ak already hoisted)
            const int tok = tq * 16 + l16;
            if (tok < 49) {
                float4 v0; v0.x = O0[0] * inv; v0.y = O0[1] * inv; v0.z = O0[2] * inv; v0.w = O0[3] * inv;
                float4 v1; v1.x = O1[0] * inv; v1.y = O1[1] * inv; v1.z = O1[2] * inv; v1.w = O1[3] * inv;
                *(ushort4*)&pool[K_OFF + tok * KP + h * 32 + lg * 4]      = cvt4(v0);
                *(ushort4*)&pool[K_OFF + tok * KP + h * 32 + 16 + lg * 4] = cvt4(v1);
            }
        }
        __syncthreads();   // BAR_o: all attn-out visible; x fully consumed

        // -------- stage next window's x (x dead: all QKV reads pre-BAR_o) --------
        if (pf) {
            const float* xp1 = x + (size_t)(win + 1) * 6272;
#pragma unroll
            for (int it = 0; it < 7; ++it) {
                const int e = it * 1024 + tid * 4;
                if (e < 6272) {
                    float4 v = *(const float4*)(xp1 + e);
                    *(ushort4*)&pool[X_OFF + (e >> 7) * XP + (e & 127)] = cvt4(v);
                }
            }
        }

        // -------- proj: out^T = proj_w * aout^T (reads k-region overlay) --------
        {
            uintptr_t wpu = (uintptr_t)wpr;
            asm volatile("" : "+s"(wpu));
            const unsigned short* wpx = (const unsigned short*)wpu;
#pragma unroll
            for (int wt = 0; wt < 2; ++wt) {
                bf16x8 wp_[4];
#pragma unroll
                for (int ks = 0; ks < 4; ++ks)
                    wp_[ks] = *(const bf16x8*)&wpx[(size_t)(((2 * h + wt) * 4 + ks) * 64 + lane) * 8];
                const float4 pbv = *(const float4*)(proj_b + h * 32 + wt * 16 + lg * 4);
#pragma unroll
                for (int nt4 = 0; nt4 < 4; ++nt4) {
                    f32x4 pc = (f32x4){0.f, 0.f, 0.f, 0.f};
#pragma unroll
                    for (int ks = 0; ks < 4; ++ks) {
                        const bf16x8 bfr = *(const bf16x8*)&pool[K_OFF + (nt4 * 16 + l16) * KP + ks * 32 + lg * 8];
                        pc = __builtin_amdgcn_mfma_f32_16x16x32_bf16(wp_[ks], bfr, pc, 0, 0, 0);
                    }
                    const int tok = nt4 * 16 + l16;
                    if (tok < 49) {
                        float4 o;
                        o.x = pc[0] + pbv.x; o.y = pc[1] + pbv.y;
                        o.z = pc[2] + pbv.z; o.w = pc[3] + pbv.w;
                        *(float4*)(out + ((size_t)win * 49 + tok) * 128 + h * 32 + wt * 16 + lg * 4) = o;
                    }
                }
            }
        }
        __syncthreads();   // BAR_x: proj reads done; next QKV may write k/vt, read new x
    }
}

extern "C" void kernel_launch(void* const* d_in, const int* in_sizes, int n_in,
                              void* d_out, int out_size, void* d_ws, size_t ws_size,
                              hipStream_t stream) {
    const float* x          = (const float*)d_in[0];
    const float* mask       = (const float*)d_in[1];
    const float* qkv_w      = (const float*)d_in[2];
    const float* qkv_b      = (const float*)d_in[3];
    const float* proj_w     = (const float*)d_in[4];
    const float* proj_b     = (const float*)d_in[5];
    const float* bias_table = (const float*)d_in[6];
    const int*   rel_index  = (const int*)d_in[7];
    float* out = (float*)d_out;
    (void)in_sizes; (void)n_in; (void)ws_size; (void)out_size;

    float* comb = (float*)d_ws;
    unsigned short* wq = (unsigned short*)((char*)d_ws + COMB_BYTES);
    unsigned short* wp = wq + WQ_USHORTS;

    prep_weights<<<dim3(16), dim3(512), 0, stream>>>(qkv_w, proj_w, wq, wp);
    prep_comb<<<dim3(19208), dim3(512), 0, stream>>>(mask, bias_table, rel_index, comb);
    winattn_kernel<<<dim3(NBLK), dim3(THREADS), 0, stream>>>(
        x, comb, wq, wp, qkv_b, proj_b, out);
}

// Round 13
// 426.545 us; speedup vs baseline: 1.1680x; 1.1680x over previous
//
#include <hip/hip_runtime.h>
#include <hip/hip_bf16.h>

#define THREADS 512
#define WPB 8
#define NWIN 16384
#define NBLK (NWIN / WPB)

typedef short bf16x8 __attribute__((ext_vector_type(8)));
typedef float f32x4 __attribute__((ext_vector_type(4)));

// ---- LDS pool (ushort units), 53,600 B -> 3 blocks/CU (24 waves).
// xa: [49][136] bf16 (x staging, then attn-out overlay)
// qk: [49][264] bf16 (cols 0..255 = q|k channels; rows 49-63 zero forever)
// vt: [128][56] bf16 (v transposed; cols 49-55 pad; +32 ush zero guard)
// Prologue zeroes qk+vt+guard; all deliberate over-reads land on finite bf16.
#define XAP 136
#define QKP 264
#define VTP 56
#define XA_OFF 0
#define QK_OFF 6664
#define VT_OFF 19600
#define POOL_USHORTS 26800      // 53,600 B

#define LOG2E 1.4426950408889634f
#define SCALE_Q 0.17677669529663689f   // 32^-0.5

// ws layout: comb[1024][4][49][52] f32, then wq, then wp fragments
#define COMB_FLOATS (1024 * 4 * 49 * 52)
#define COMB_BYTES  ((size_t)COMB_FLOATS * 4)
#define WQ_USHORTS (96 * 64 * 8)
#define WP_USHORTS (32 * 64 * 8)

static __device__ __forceinline__ unsigned short f2bf(float x) {
    union { __hip_bfloat16 b; unsigned short u; } c;
    c.b = __float2bfloat16(x);
    return c.u;
}
static __device__ __forceinline__ unsigned pack2bf(float lo, float hi) {
    return (unsigned)f2bf(lo) | ((unsigned)f2bf(hi) << 16);
}
static __device__ __forceinline__ ushort4 cvt4(float4 v) {
    ushort4 u; u.x = f2bf(v.x); u.y = f2bf(v.y); u.z = f2bf(v.z); u.w = f2bf(v.w);
    return u;
}

// ---------------- prep: fp32 weights -> pre-swizzled bf16 fragments ----------------
__global__ __launch_bounds__(512)
void prep_weights(const float* __restrict__ qkv_w, const float* __restrict__ proj_w,
                  unsigned short* __restrict__ wq, unsigned short* __restrict__ wp)
{
    const int t = blockIdx.x * 512 + threadIdx.x;
    if (t < 96 * 64) {
        const int lane = t & 63, g = t >> 6;
        const int l16 = lane & 15, lg = lane >> 4;
        const int ks = g & 3, wn = g >> 2;                 // wn = wave*3+nt
        const int ch = wn * 16 + l16;                      // qkv output channel
        const float s = (ch < 128) ? (SCALE_Q * LOG2E) : 1.0f;
        const float* p = qkv_w + (size_t)ch * 128 + ks * 32 + lg * 8;
        bf16x8 f;
#pragma unroll
        for (int j = 0; j < 8; ++j) f[j] = (short)f2bf(p[j] * s);
        *(bf16x8*)&wq[(size_t)t * 8] = f;
    } else if (t < 96 * 64 + 32 * 64) {
        const int t2 = t - 96 * 64;
        const int lane = t2 & 63, g = t2 >> 6;             // g = wave*4+ks
        const int l16 = lane & 15, lg = lane >> 4;
        const int ks = g & 3, wv = g >> 2;
        const float* p = proj_w + (size_t)(wv * 16 + l16) * 128 + ks * 32 + lg * 8;
        bf16x8 f;
#pragma unroll
        for (int j = 0; j < 8; ++j) f[j] = (short)f2bf(p[j]);
        *(bf16x8*)&wp[(size_t)t2 * 8] = f;
    }
}

// ---------------- prep: comb[wi][h][qt][52] = (mask + rel_bias) * log2e ----------------
__global__ __launch_bounds__(512)
void prep_comb(const float* __restrict__ mask, const float* __restrict__ bias_table,
               const int* __restrict__ rel_index, float* __restrict__ comb)
{
    const unsigned t = blockIdx.x * 512 + threadIdx.x;
    if (t >= 1024u * 4u * 49u * 49u) return;
    const unsigned wi = t / 9604u;            // 4*49*49
    const unsigned r1 = t - wi * 9604u;
    const unsigned h  = r1 / 2401u;
    const unsigned r2 = r1 - h * 2401u;       // qt*49 + kt
    const unsigned qt = r2 / 49u;
    const unsigned kt = r2 - qt * 49u;
    const float m = mask[wi * 2401u + r2];
    const float b = bias_table[rel_index[r2] * 4 + h];
    comb[(((size_t)wi * 4u + h) * 49u + qt) * 52u + kt] = (m + b) * LOG2E;
}

__global__ __launch_bounds__(THREADS, 4)
void winattn_kernel(const float* __restrict__ x, const float* __restrict__ comb,
                    const unsigned short* __restrict__ wq, const unsigned short* __restrict__ wpr,
                    const float* __restrict__ qkv_b, const float* __restrict__ proj_b,
                    float* __restrict__ out)
{
    __shared__ __align__(16) unsigned short pool[POOL_USHORTS];

    const int tid  = threadIdx.x;
    const int wave = tid >> 6;
    const int lane = tid & 63;
    const int lg   = lane >> 4;
    const int l16  = lane & 15;
    const int h    = wave >> 1;      // head
    const int mh   = wave & 1;       // q-half (32 tokens)

    const float4 pb = *(const float4*)(proj_b + wave * 16 + lg * 4);

    // PV fragment-permute lane indices (P: C-layout -> B-frag layout, same l16/q col)
    const int idxA = l16 + 2 * (lane & 16);    // l16 + 32*(lg&1)
    const int idxB = idxA + 16;
    const bool hiSel = (lane & 32) != 0;       // lg&2

    const int win0 = blockIdx.x * WPB;

    // ---------------- prologue: zero qk+vt+guard, stage window 0 ----------------
    {
        unsigned* p32 = (unsigned*)pool;
        for (int i = QK_OFF / 2 + tid; i < POOL_USHORTS / 2; i += THREADS) p32[i] = 0;
    }
#pragma unroll
    for (int it = 0; it < 4; ++it) {
        const int e = it * 2048 + tid * 4;
        if (e < 6272) {
            float4 v = *(const float4*)(x + (size_t)win0 * 6272 + e);
            *(ushort4*)&pool[XA_OFF + (e >> 7) * XAP + (e & 127)] = cvt4(v);
        }
    }
    __syncthreads();

    for (int w = 0; w < WPB; ++w) {
        const int win = win0 + w;
        const bool pf = (w + 1 < WPB);

        // -------- QKV GEMM, nt-outer (one 16-reg wB tile live at a time) --------
        {
            uintptr_t wqu = (uintptr_t)wq;
            asm volatile("" : "+s"(wqu));
            const unsigned short* wqx = (const unsigned short*)wqu;
#pragma unroll
            for (int nt = 0; nt < 3; ++nt) {
                bf16x8 wB[4];
#pragma unroll
                for (int ks = 0; ks < 4; ++ks)
                    wB[ks] = *(const bf16x8*)&wqx[(size_t)(((wave * 3 + nt) * 4 + ks) * 64 + lane) * 8];
                const int chB = wave * 48 + nt * 16;
                float4 qb4;
                if (chB < 256) {
                    qb4 = *(const float4*)(qkv_b + chB + lg * 4);
                    if (chB < 128) { qb4.x *= SCALE_Q * LOG2E; qb4.y *= SCALE_Q * LOG2E;
                                     qb4.z *= SCALE_Q * LOG2E; qb4.w *= SCALE_Q * LOG2E; }
                } else {
                    qb4.x = qkv_b[chB + l16];
                }
#pragma unroll
                for (int mt = 0; mt < 4; ++mt) {
                    bf16x8 xf[4];
#pragma unroll
                    for (int ks = 0; ks < 4; ++ks)
                        xf[ks] = *(const bf16x8*)&pool[XA_OFF + (mt * 16 + l16) * XAP + ks * 32 + lg * 8];
                    f32x4 acc = (f32x4){0.f, 0.f, 0.f, 0.f};
                    if (chB < 256) {
#pragma unroll
                        for (int ks = 0; ks < 4; ++ks)
                            acc = __builtin_amdgcn_mfma_f32_16x16x32_bf16(wB[ks], xf[ks], acc, 0, 0, 0);
                        const int tok = mt * 16 + l16;
                        if (tok < 49) {
                            float4 v; v.x = acc[0] + qb4.x; v.y = acc[1] + qb4.y;
                            v.z = acc[2] + qb4.z; v.w = acc[3] + qb4.w;
                            *(ushort4*)&pool[QK_OFF + tok * QKP + chB + lg * 4] = cvt4(v);
                        }
                    } else {
#pragma unroll
                        for (int ks = 0; ks < 4; ++ks)
                            acc = __builtin_amdgcn_mfma_f32_16x16x32_bf16(xf[ks], wB[ks], acc, 0, 0, 0);
                        const int vcol = mt * 16 + lg * 4;     // token index (C rows)
                        if (vcol <= 48) {   // tokens 49-51 land in pad cols; >=52 skipped
                            const float vb = qb4.x;
                            float4 v; v.x = acc[0] + vb; v.y = acc[1] + vb;
                            v.z = acc[2] + vb; v.w = acc[3] + vb;
                            *(ushort4*)&pool[VT_OFF + (chB - 256 + l16) * VTP + vcol] = cvt4(v);
                        }
                    }
                }
            }
        }
        __syncthreads();   // BAR1: q/k/v visible; xa's x consumed

        // -------- attention: S' = K * Q^T; logits = S + comb; no-max softmax --------
        const float* combW = comb + ((size_t)((win & 1023) * 4 + h)) * (49 * 52);
        float inv[2];
        unsigned pk[2][4][2];
#pragma unroll
        for (int nt = 0; nt < 2; ++nt) {
            const int qt = mh * 32 + nt * 16 + l16;
            const int qrow = (qt > 48) ? 48 : qt;
            const float* crow = combW + qrow * 52;
            const float4 c0 = *(const float4*)(crow + lg * 4);
            const float4 c1 = *(const float4*)(crow + 16 + lg * 4);
            const float4 c2 = *(const float4*)(crow + 32 + lg * 4);
            const float  c3 = crow[48];
            const bf16x8 bq = *(const bf16x8*)&pool[QK_OFF + qt * QKP + h * 32 + lg * 8];
            f32x4 S[4];
            __builtin_amdgcn_s_setprio(1);
#pragma unroll
            for (int mt = 0; mt < 4; ++mt) {
                const bf16x8 ak = *(const bf16x8*)&pool[QK_OFF + (mt * 16 + l16) * QKP + 128 + h * 32 + lg * 8];
                S[mt] = __builtin_amdgcn_mfma_f32_16x16x32_bf16(ak, bq, (f32x4){0.f,0.f,0.f,0.f}, 0, 0, 0);
            }
            __builtin_amdgcn_s_setprio(0);
            float lv[12];
            lv[0] = S[0][0] + c0.x; lv[1] = S[0][1] + c0.y;
            lv[2] = S[0][2] + c0.z; lv[3] = S[0][3] + c0.w;
            lv[4] = S[1][0] + c1.x; lv[5] = S[1][1] + c1.y;
            lv[6] = S[1][2] + c1.z; lv[7] = S[1][3] + c1.w;
            lv[8] = S[2][0] + c2.x; lv[9] = S[2][1] + c2.y;
            lv[10] = S[2][2] + c2.z; lv[11] = S[2][3] + c2.w;
            const float lv3 = (lg == 0) ? (S[3][0] + c3) : -1e30f;   // kt=48; kt>48 masked

            float sum = 0.f;
#pragma unroll
            for (int i = 0; i < 12; ++i) {
                const float p = exp2f(lv[i]);
                lv[i] = p;
                sum += p;
            }
            const float p3 = exp2f(lv3);
            sum += p3;
            sum += __shfl_xor(sum, 16);
            sum += __shfl_xor(sum, 32);
            inv[nt] = 1.0f / sum;
            pk[nt][0][0] = pack2bf(lv[0], lv[1]);  pk[nt][0][1] = pack2bf(lv[2], lv[3]);
            pk[nt][1][0] = pack2bf(lv[4], lv[5]);  pk[nt][1][1] = pack2bf(lv[6], lv[7]);
            pk[nt][2][0] = pack2bf(lv[8], lv[9]);  pk[nt][2][1] = pack2bf(lv[10], lv[11]);
            pk[nt][3][0] = pack2bf(p3, 0.f);       pk[nt][3][1] = 0u;
        }

        // -------- PV: O' = V^T * P^T; P B-fragments built via cross-lane shfl --------
        f32x4 O[2][2];   // [dim-tile][tok-tile]
#pragma unroll
        for (int i = 0; i < 2; ++i)
#pragma unroll
            for (int j = 0; j < 2; ++j) O[i][j] = (f32x4){0.f, 0.f, 0.f, 0.f};
#pragma unroll
        for (int kh = 0; kh < 2; ++kh) {
            bf16x8 bv[2];
#pragma unroll
            for (int i = 0; i < 2; ++i)
                bv[i] = *(const bf16x8*)&pool[VT_OFF + (h * 32 + i * 16 + l16) * VTP + kh * 32 + lg * 8];
#pragma unroll
            for (int j = 0; j < 2; ++j) {
                const unsigned s0a = (unsigned)__shfl((int)pk[j][2 * kh + 0][0], idxA, 64);
                const unsigned s0b = (unsigned)__shfl((int)pk[j][2 * kh + 1][0], idxA, 64);
                const unsigned s1a = (unsigned)__shfl((int)pk[j][2 * kh + 0][1], idxA, 64);
                const unsigned s1b = (unsigned)__shfl((int)pk[j][2 * kh + 1][1], idxA, 64);
                const unsigned s2a = (unsigned)__shfl((int)pk[j][2 * kh + 0][0], idxB, 64);
                const unsigned s2b = (unsigned)__shfl((int)pk[j][2 * kh + 1][0], idxB, 64);
                const unsigned s3a = (unsigned)__shfl((int)pk[j][2 * kh + 0][1], idxB, 64);
                const unsigned s3b = (unsigned)__shfl((int)pk[j][2 * kh + 1][1], idxB, 64);
                unsigned pau[4];
                pau[0] = hiSel ? s0b : s0a;
                pau[1] = hiSel ? s1b : s1a;
                pau[2] = hiSel ? s2b : s2a;
                pau[3] = hiSel ? s3b : s3a;
                const bf16x8 pa = *(const bf16x8*)pau;
                __builtin_amdgcn_s_setprio(1);
#pragma unroll
                for (int i = 0; i < 2; ++i)
                    O[i][j] = __builtin_amdgcn_mfma_f32_16x16x32_bf16(bv[i], pa, O[i][j], 0, 0, 0);
                __builtin_amdgcn_s_setprio(0);
            }
        }
        // attn-out -> xa overlay (row write along dims), fold 1/sum
#pragma unroll
        for (int j = 0; j < 2; ++j) {
            const int tok = mh * 32 + j * 16 + l16;
            if (tok < 49) {
#pragma unroll
                for (int i = 0; i < 2; ++i) {
                    float4 v;
                    v.x = O[i][j][0] * inv[j]; v.y = O[i][j][1] * inv[j];
                    v.z = O[i][j][2] * inv[j]; v.w = O[i][j][3] * inv[j];
                    *(ushort4*)&pool[XA_OFF + tok * XAP + h * 32 + i * 16 + lg * 4] = cvt4(v);
                }
            }
        }
        __syncthreads();   // BAR2: attn-out visible

        // -------- proj: out^T = proj_w * aout^T (coalesced float4 store) --------
        bf16x8 wp_[4];
        {
            uintptr_t wpu = (uintptr_t)wpr;
            asm volatile("" : "+s"(wpu));
            const unsigned short* wpx = (const unsigned short*)wpu;
#pragma unroll
            for (int ks = 0; ks < 4; ++ks)
                wp_[ks] = *(const bf16x8*)&wpx[(size_t)((wave * 4 + ks) * 64 + lane) * 8];
        }
#pragma unroll
        for (int nt4 = 0; nt4 < 4; ++nt4) {
            const int tr = nt4 * 16 + l16;
            f32x4 pc = (f32x4){0.f, 0.f, 0.f, 0.f};
#pragma unroll
            for (int ks = 0; ks < 4; ++ks) {
                const bf16x8 bfr = *(const bf16x8*)&pool[XA_OFF + tr * XAP + ks * 32 + lg * 8];
                pc = __builtin_amdgcn_mfma_f32_16x16x32_bf16(wp_[ks], bfr, pc, 0, 0, 0);
            }
            if (tr < 49) {
                float4 o;
                o.x = pc[0] + pb.x; o.y = pc[1] + pb.y;
                o.z = pc[2] + pb.z; o.w = pc[3] + pb.w;
                *(float4*)(out + ((size_t)win * 49 + tr) * 128 + wave * 16 + lg * 4) = o;
            }
        }
        __syncthreads();   // BAR3: proj's xa reads done

        // -------- stage next window's x (global -> cvt -> LDS; covered by
        //          the two other co-resident blocks) --------
        if (pf) {
            const float* xp1 = x + (size_t)(win + 1) * 6272;
#pragma unroll
            for (int it = 0; it < 4; ++it) {
                const int e = it * 2048 + tid * 4;
                if (e < 6272) {
                    float4 v = *(const float4*)(xp1 + e);
                    *(ushort4*)&pool[XA_OFF + (e >> 7) * XAP + (e & 127)] = cvt4(v);
                }
            }
        }
        __syncthreads();   // BAR4: next window's x staged
    }
}

extern "C" void kernel_launch(void* const* d_in, const int* in_sizes, int n_in,
                              void* d_out, int out_size, void* d_ws, size_t ws_size,
                              hipStream_t stream) {
    const float* x          = (const float*)d_in[0];
    const float* mask       = (const float*)d_in[1];
    const float* qkv_w      = (const float*)d_in[2];
    const float* qkv_b      = (const float*)d_in[3];
    const float* proj_w     = (const float*)d_in[4];
    const float* proj_b     = (const float*)d_in[5];
    const float* bias_table = (const float*)d_in[6];
    const int*   rel_index  = (const int*)d_in[7];
    float* out = (float*)d_out;
    (void)in_sizes; (void)n_in; (void)ws_size; (void)out_size;

    float* comb = (float*)d_ws;
    unsigned short* wq = (unsigned short*)((char*)d_ws + COMB_BYTES);
    unsigned short* wp = wq + WQ_USHORTS;

    prep_weights<<<dim3(16), dim3(512), 0, stream>>>(qkv_w, proj_w, wq, wp);
    prep_comb<<<dim3(19208), dim3(512), 0, stream>>>(mask, bias_table, rel_index, comb);
    winattn_kernel<<<dim3(NBLK), dim3(THREADS), 0, stream>>>(
        x, comb, wq, wp, qkv_b, proj_b, out);
}